// Round 1
// baseline (2137.200 us; speedup 1.0000x reference)
//
#include <hip/hip_runtime.h>

#define N_NODES 100000
#define D 128

// ---------------- degree helpers ----------------

__global__ __launch_bounds__(256) void zero_deg(int* deg, int n) {
    int i = blockIdx.x * 256 + threadIdx.x;
    if (i < n) deg[i] = 0;
}

__global__ __launch_bounds__(256) void deg_count(const int* __restrict__ ei, int n_edges,
                                                 int shape, int* __restrict__ deg) {
    int e = blockIdx.x * 256 + threadIdx.x;
    if (e < n_edges) {
        int dest = ei[(long)n_edges * shape + (long)e * shape];  // row 1, first slot of hyperedge
        atomicAdd(&deg[dest], 1);
    }
}

// ---------------- dense: out = x @ C_w + C_b ----------------

__global__ __launch_bounds__(256) void dense_kernel(const float* __restrict__ x,
                                                    const float* __restrict__ Cw,
                                                    const float* __restrict__ Cb,
                                                    float* __restrict__ out) {
    int j = threadIdx.x & 127;
    int row = blockIdx.x * 2 + (threadIdx.x >> 7);
    if (row >= N_NODES) return;
    const float* xr = x + (long)row * D;
    float acc = Cb[j];
#pragma unroll
    for (int k = 0; k < D; k += 4) {
        float4 xv = *(const float4*)(xr + k);
        acc = fmaf(xv.x, Cw[(k + 0) * D + j], acc);
        acc = fmaf(xv.y, Cw[(k + 1) * D + j], acc);
        acc = fmaf(xv.z, Cw[(k + 2) * D + j], acc);
        acc = fmaf(xv.w, Cw[(k + 3) * D + j], acc);
    }
    out[(long)row * D + j] = acc;
}

// ---------------- edge gather-GEMM-scatter ----------------
// Tile: 32 edges x 128 cols, K = SHAPE*128, BK = 32.
// Thread t: col group jg = t&31 (4 cols), edge group eg = t>>5 (4 edges) -> 4x4 register tile.

template <int SHAPE>
__global__ __launch_bounds__(256) void edge_kernel(const float* __restrict__ x,
                                                   const int* __restrict__ ei,
                                                   const float* __restrict__ A,
                                                   const int* __restrict__ deg,
                                                   float* __restrict__ out, int n_edges) {
    constexpr int K = SHAPE * D;
    constexpr int BK = 32;
    constexpr int TE = 32;
    __shared__ float At[BK][D];       // 16 KB
    __shared__ float Gt[TE][BK + 4];  // pad to 36 floats stride (16B-aligned), 4.5 KB

    const int t = threadIdx.x;
    const int jg = t & 31;
    const int eg = t >> 5;
    const int e_base = blockIdx.x * TE;

    float acc[4][4] = {};

    for (int k0 = 0; k0 < K; k0 += BK) {
        __syncthreads();
        // stage A tile: rows k0..k0+31, all 128 cols (coalesced float4)
        {
            int c = (t & 31) * 4;
            int r = t >> 5;
#pragma unroll
            for (int rep = 0; rep < 4; rep++) {
                int kk = r + rep * 8;
                *(float4*)&At[kk][c] = *(const float4*)&A[(long)(k0 + kk) * D + c];
            }
        }
        // stage gathered G tile: 32 edges x 32 k (one x-row segment per edge; slot fixed per k-block)
        {
            int el = t >> 3;            // 0..31: edge within tile
            int c = (t & 7) * 4;        // 0..28: col within k-block
            int e = e_base + el;
            int ec = e < n_edges ? e : n_edges - 1;  // clamp OOB (result discarded)
            int slot = k0 >> 7;
            int src = ei[(long)ec * SHAPE + slot];
            const float* xr = x + (long)src * D + (k0 & 127);
            *(float4*)&Gt[el][c] = *(const float4*)(xr + c);
        }
        __syncthreads();
#pragma unroll
        for (int kk = 0; kk < BK; kk += 4) {
            float4 av[4];
#pragma unroll
            for (int i = 0; i < 4; i++) av[i] = *(const float4*)&At[kk + i][jg * 4];
            float4 gv[4];
#pragma unroll
            for (int e = 0; e < 4; e++) gv[e] = *(const float4*)&Gt[eg * 4 + e][kk];
#pragma unroll
            for (int e = 0; e < 4; e++) {
                const float* g = (const float*)&gv[e];
#pragma unroll
                for (int i = 0; i < 4; i++) {
                    acc[e][0] = fmaf(g[i], av[i].x, acc[e][0]);
                    acc[e][1] = fmaf(g[i], av[i].y, acc[e][1]);
                    acc[e][2] = fmaf(g[i], av[i].z, acc[e][2]);
                    acc[e][3] = fmaf(g[i], av[i].w, acc[e][3]);
                }
            }
        }
    }

    // epilogue: normalize by per-type in-degree, scatter-add
    const long ntot = (long)n_edges * SHAPE;
#pragma unroll
    for (int e = 0; e < 4; e++) {
        int edge = e_base + eg * 4 + e;
        if (edge < n_edges) {
            int dstn = ei[ntot + (long)edge * SHAPE];
            float inv = 1.0f / (float)deg[dstn];
            float* op = out + (long)dstn * D + jg * 4;
            atomicAdd(op + 0, acc[e][0] * inv);
            atomicAdd(op + 1, acc[e][1] * inv);
            atomicAdd(op + 2, acc[e][2] * inv);
            atomicAdd(op + 3, acc[e][3] * inv);
        }
    }
}

// ---------------- launcher ----------------

extern "C" void kernel_launch(void* const* d_in, const int* in_sizes, int n_in,
                              void* d_out, int out_size, void* d_ws, size_t ws_size,
                              hipStream_t stream) {
    const float* x  = (const float*)d_in[0];
    const float* A1 = (const float*)d_in[1];
    const float* A2 = (const float*)d_in[2];
    const float* A3 = (const float*)d_in[3];
    const float* Cw = (const float*)d_in[4];
    const float* Cb = (const float*)d_in[5];
    const int* e1 = (const int*)d_in[6];
    const int* e2 = (const int*)d_in[7];
    const int* e3 = (const int*)d_in[8];
    float* out = (float*)d_out;

    int* deg1 = (int*)d_ws;
    int* deg2 = deg1 + N_NODES;
    int* deg3 = deg2 + N_NODES;

    const int NE1 = in_sizes[6] / 2;        // 400000
    const int NE2 = in_sizes[7] / (2 * 2);  // 300000
    const int NE3 = in_sizes[8] / (2 * 3);  // 200000

    // 1) zero degree arrays (ws is poisoned each call)
    zero_deg<<<(3 * N_NODES + 255) / 256, 256, 0, stream>>>(deg1, 3 * N_NODES);

    // 2) per-type in-degree counts
    deg_count<<<(NE1 + 255) / 256, 256, 0, stream>>>(e1, NE1, 1, deg1);
    deg_count<<<(NE2 + 255) / 256, 256, 0, stream>>>(e2, NE2, 2, deg2);
    deg_count<<<(NE3 + 255) / 256, 256, 0, stream>>>(e3, NE3, 3, deg3);

    // 3) dense term (initializes out)
    dense_kernel<<<(N_NODES + 1) / 2, 256, 0, stream>>>(x, Cw, Cb, out);

    // 4) edge aggregations (atomic-add into out)
    edge_kernel<1><<<(NE1 + 31) / 32, 256, 0, stream>>>(x, e1, A1, deg1, out, NE1);
    edge_kernel<2><<<(NE2 + 31) / 32, 256, 0, stream>>>(x, e2, A2, deg2, out, NE2);
    edge_kernel<3><<<(NE3 + 31) / 32, 256, 0, stream>>>(x, e3, A3, deg3, out, NE3);
}

// Round 2
// 1881.107 us; speedup vs baseline: 1.1361x; 1.1361x over previous
//
#include <hip/hip_runtime.h>

#define N_NODES 100000
#define D 128
#define NTOT (3 * N_NODES)

// ---------------- ws layout (ints) ----------------
// deg    @ 0          (300000)   per-type in-degree, [type*100000 + dest]
// offs   @ 300000     (300001)   exclusive scan of deg (+ sentinel)
// cursor @ 600001     (300000)   scatter cursors (init = offs)
// csr    @ 900001     (900000)   edge ids bucketed by (type,dest)
// bsums  @ 1800001    (512)
// boffs  @ 1800513    (512)

// ---------------- degree / CSR build ----------------

__global__ __launch_bounds__(256) void zero_deg(int* deg, int n) {
    int i = blockIdx.x * 256 + threadIdx.x;
    if (i < n) deg[i] = 0;
}

__global__ __launch_bounds__(256) void deg_count(const int* __restrict__ ei, int n_edges,
                                                 int shape, int* __restrict__ deg) {
    int e = blockIdx.x * 256 + threadIdx.x;
    if (e < n_edges) {
        int dest = ei[(long)n_edges * shape + (long)e * shape];
        atomicAdd(&deg[dest], 1);
    }
}

// S1: per-block (1024 elems) sums
__global__ __launch_bounds__(256) void scan_reduce(const int* __restrict__ deg,
                                                   int* __restrict__ bsums, int n) {
    __shared__ int s[256];
    int t = threadIdx.x;
    int base = blockIdx.x * 1024 + t * 4;
    int loc = 0;
#pragma unroll
    for (int r = 0; r < 4; r++) {
        int idx = base + r;
        if (idx < n) loc += deg[idx];
    }
    s[t] = loc;
    for (int off = 128; off > 0; off >>= 1) {
        __syncthreads();
        if (t < off) s[t] += s[t + off];
    }
    if (t == 0) bsums[blockIdx.x] = s[0];
}

// S2: scan of block sums (single block, 512 threads)
__global__ __launch_bounds__(512) void scan_tops(const int* __restrict__ bsums,
                                                 int* __restrict__ boffs,
                                                 int* __restrict__ offs, int nb, int n) {
    __shared__ int s[512];
    int t = threadIdx.x;
    int v = (t < nb) ? bsums[t] : 0;
    s[t] = v;
    for (int off = 1; off < 512; off <<= 1) {
        __syncthreads();
        int x = (t >= off) ? s[t - off] : 0;
        __syncthreads();
        s[t] += x;
    }
    if (t < nb) boffs[t] = s[t] - v;
    if (t == nb - 1) offs[n] = s[t];  // sentinel = total edge count
}

// S3: final exclusive scan, write offs + cursor
__global__ __launch_bounds__(256) void scan_final(const int* __restrict__ deg,
                                                  const int* __restrict__ boffs,
                                                  int* __restrict__ offs,
                                                  int* __restrict__ cursor, int n) {
    __shared__ int s[256];
    int t = threadIdx.x;
    int base = blockIdx.x * 1024 + t * 4;
    int v[4], p[4];
#pragma unroll
    for (int r = 0; r < 4; r++) {
        int idx = base + r;
        v[r] = (idx < n) ? deg[idx] : 0;
    }
    p[0] = 0; p[1] = v[0]; p[2] = v[0] + v[1]; p[3] = v[0] + v[1] + v[2];
    int tsum = p[3] + v[3];
    s[t] = tsum;
    for (int off = 1; off < 256; off <<= 1) {
        __syncthreads();
        int x = (t >= off) ? s[t - off] : 0;
        __syncthreads();
        s[t] += x;
    }
    int texcl = s[t] - tsum + boffs[blockIdx.x];
#pragma unroll
    for (int r = 0; r < 4; r++) {
        int idx = base + r;
        if (idx < n) {
            int val = texcl + p[r];
            offs[idx] = val;
            cursor[idx] = val;
        }
    }
}

__global__ __launch_bounds__(256) void scatter_edges(const int* __restrict__ ei, int n_edges,
                                                     int shape, int* __restrict__ cursor,
                                                     int* __restrict__ csr) {
    int e = blockIdx.x * 256 + threadIdx.x;
    if (e < n_edges) {
        int dest = ei[(long)n_edges * shape + (long)e * shape];
        int pos = atomicAdd(&cursor[dest], 1);
        csr[pos] = e;
    }
}

// ---------------- fused single-writer kernel ----------------
// One block per 16 dest nodes. LDS accumulator acc[16][132] (pad vs bank conflicts).
// Per type: CSR range -> 32-edge row tiles -> fp32 GEMM (R1 structure) -> LDS atomic
// accumulate scaled by 1/deg. Dense term = virtual 16-row tile with A=C_w, inv=1.

template <int SHAPE, bool DENSE>
__device__ __forceinline__ void process_type(
    const float* __restrict__ x, const float* __restrict__ A,
    const int* __restrict__ ei, const int* __restrict__ deg_t,
    const int* __restrict__ offs, const int* __restrict__ csr,
    int n_edges, int tbase, int d0, int t,
    float (&acc)[16][132], float (&At)[32][128], float (&Gt)[32][36],
    int (&ssrc)[32][3], float (&sinv)[32], int (&sdl)[32]) {
    constexpr int K = SHAPE * D;
    int start, end;
    if (DENSE) {
        start = 0; end = 16;
    } else {
        start = offs[tbase + d0];
        end = offs[tbase + d0 + 16];
    }

    const int jg = t & 31;
    const int eg = t >> 5;

    for (int tile = start; tile < end; tile += 32) {
        __syncthreads();  // previous tile's readers done
        if (t < 32) {
            int p = tile + t;
            bool valid = DENSE ? (t < 16) : (p < end);
            int dl = 0;
            float inv = 0.0f;
            if (DENSE) {
                dl = t & 15;
                ssrc[t][0] = valid ? (d0 + t) : 0;
                inv = valid ? 1.0f : 0.0f;
            } else {
                if (valid) {
                    int e = csr[p];
                    int dest = ei[(long)n_edges * SHAPE + (long)e * SHAPE];
                    dl = dest - d0;
                    inv = 1.0f / (float)deg_t[dest];
#pragma unroll
                    for (int s = 0; s < SHAPE; s++) ssrc[t][s] = ei[(long)e * SHAPE + s];
                } else {
#pragma unroll
                    for (int s = 0; s < SHAPE; s++) ssrc[t][s] = 0;
                }
            }
            sdl[t] = dl;
            sinv[t] = inv;
        }
        __syncthreads();

        float lacc[4][4] = {};
        for (int k0 = 0; k0 < K; k0 += 32) {
            if (k0) __syncthreads();
            // stage A tile (rows k0..k0+31, 128 cols)
            {
                int c = (t & 31) * 4;
                int r = t >> 5;
#pragma unroll
                for (int rep = 0; rep < 4; rep++) {
                    int kk = r + rep * 8;
                    *(float4*)&At[kk][c] = *(const float4*)&A[(long)(k0 + kk) * D + c];
                }
            }
            // stage gathered tile (32 rows x 32 k)
            {
                int el = t >> 3;
                int c = (t & 7) * 4;
                int slot = k0 >> 7;
                int src = ssrc[el][slot];
                const float* xr = x + (long)src * D + (k0 & 127);
                *(float4*)&Gt[el][c] = *(const float4*)(xr + c);
            }
            __syncthreads();
#pragma unroll
            for (int kk = 0; kk < 32; kk += 4) {
                float4 av[4];
#pragma unroll
                for (int i = 0; i < 4; i++) av[i] = *(const float4*)&At[kk + i][jg * 4];
                float4 gv[4];
#pragma unroll
                for (int e = 0; e < 4; e++) gv[e] = *(const float4*)&Gt[eg * 4 + e][kk];
#pragma unroll
                for (int e = 0; e < 4; e++) {
                    const float* g = (const float*)&gv[e];
#pragma unroll
                    for (int i = 0; i < 4; i++) {
                        lacc[e][0] = fmaf(g[i], av[i].x, lacc[e][0]);
                        lacc[e][1] = fmaf(g[i], av[i].y, lacc[e][1]);
                        lacc[e][2] = fmaf(g[i], av[i].z, lacc[e][2]);
                        lacc[e][3] = fmaf(g[i], av[i].w, lacc[e][3]);
                    }
                }
            }
        }
        // epilogue: scaled LDS accumulate
#pragma unroll
        for (int e = 0; e < 4; e++) {
            int row = eg * 4 + e;
            float inv = sinv[row];
            if (inv != 0.0f) {
                int dl = sdl[row];
#pragma unroll
                for (int c = 0; c < 4; c++) {
                    atomicAdd(&acc[dl][jg * 4 + c], lacc[e][c] * inv);
                }
            }
        }
    }
}

__global__ __launch_bounds__(256) void fused_kernel(
    const float* __restrict__ x, const float* __restrict__ A1,
    const float* __restrict__ A2, const float* __restrict__ A3,
    const float* __restrict__ Cw, const float* __restrict__ Cb,
    const int* __restrict__ e1, const int* __restrict__ e2, const int* __restrict__ e3,
    const int* __restrict__ deg, const int* __restrict__ offs, const int* __restrict__ csr,
    float* __restrict__ out, int ne1, int ne2, int ne3) {
    __shared__ float acc[16][132];
    __shared__ float At[32][128];
    __shared__ float Gt[32][36];
    __shared__ int ssrc[32][3];
    __shared__ float sinv[32];
    __shared__ int sdl[32];

    const int t = threadIdx.x;
    const int d0 = blockIdx.x * 16;

    // init accumulator with bias
#pragma unroll
    for (int r = 0; r < 8; r++) {
        int idx = r * 256 + t;
        acc[idx >> 7][idx & 127] = Cb[idx & 127];
    }
    // dense term: out_row = x[d] @ C_w
    process_type<1, true>(x, Cw, nullptr, nullptr, offs, csr, 0, 0, d0, t,
                          acc, At, Gt, ssrc, sinv, sdl);
    // edge types
    process_type<1, false>(x, A1, e1, deg + 0 * N_NODES, offs, csr, ne1, 0 * N_NODES, d0, t,
                           acc, At, Gt, ssrc, sinv, sdl);
    process_type<2, false>(x, A2, e2, deg + 1 * N_NODES, offs, csr, ne2, 1 * N_NODES, d0, t,
                           acc, At, Gt, ssrc, sinv, sdl);
    process_type<3, false>(x, A3, e3, deg + 2 * N_NODES, offs, csr, ne3, 2 * N_NODES, d0, t,
                           acc, At, Gt, ssrc, sinv, sdl);

    __syncthreads();
    // single coalesced write
#pragma unroll
    for (int r = 0; r < 8; r++) {
        int idx = r * 256 + t;
        out[(long)(d0 + (idx >> 7)) * D + (idx & 127)] = acc[idx >> 7][idx & 127];
    }
}

// ---------------- launcher ----------------

extern "C" void kernel_launch(void* const* d_in, const int* in_sizes, int n_in,
                              void* d_out, int out_size, void* d_ws, size_t ws_size,
                              hipStream_t stream) {
    const float* x  = (const float*)d_in[0];
    const float* A1 = (const float*)d_in[1];
    const float* A2 = (const float*)d_in[2];
    const float* A3 = (const float*)d_in[3];
    const float* Cw = (const float*)d_in[4];
    const float* Cb = (const float*)d_in[5];
    const int* e1 = (const int*)d_in[6];
    const int* e2 = (const int*)d_in[7];
    const int* e3 = (const int*)d_in[8];
    float* out = (float*)d_out;

    int* ws = (int*)d_ws;
    int* deg    = ws;
    int* offs   = ws + 300000;
    int* cursor = ws + 600001;
    int* csr    = ws + 900001;
    int* bsums  = ws + 1800001;
    int* boffs  = ws + 1800513;

    const int NE1 = in_sizes[6] / 2;        // 400000
    const int NE2 = in_sizes[7] / (2 * 2);  // 300000
    const int NE3 = in_sizes[8] / (2 * 3);  // 200000
    const int n = NTOT;                     // 300000
    const int NB = (n + 1023) / 1024;       // 293

    // 1) degrees
    zero_deg<<<(n + 255) / 256, 256, 0, stream>>>(deg, n);
    deg_count<<<(NE1 + 255) / 256, 256, 0, stream>>>(e1, NE1, 1, deg + 0 * N_NODES);
    deg_count<<<(NE2 + 255) / 256, 256, 0, stream>>>(e2, NE2, 2, deg + 1 * N_NODES);
    deg_count<<<(NE3 + 255) / 256, 256, 0, stream>>>(e3, NE3, 3, deg + 2 * N_NODES);

    // 2) exclusive scan -> offs, cursor
    scan_reduce<<<NB, 256, 0, stream>>>(deg, bsums, n);
    scan_tops<<<1, 512, 0, stream>>>(bsums, boffs, offs, NB, n);
    scan_final<<<NB, 256, 0, stream>>>(deg, boffs, offs, cursor, n);

    // 3) bucket edges by (type, dest)
    scatter_edges<<<(NE1 + 255) / 256, 256, 0, stream>>>(e1, NE1, 1, cursor + 0 * N_NODES, csr);
    scatter_edges<<<(NE2 + 255) / 256, 256, 0, stream>>>(e2, NE2, 2, cursor + 1 * N_NODES, csr);
    scatter_edges<<<(NE3 + 255) / 256, 256, 0, stream>>>(e3, NE3, 3, cursor + 2 * N_NODES, csr);

    // 4) fused single-writer compute
    fused_kernel<<<N_NODES / 16, 256, 0, stream>>>(x, A1, A2, A3, Cw, Cb, e1, e2, e3,
                                                   deg, offs, csr, out, NE1, NE2, NE3);
}

// Round 3
// 1087.255 us; speedup vs baseline: 1.9657x; 1.7301x over previous
//
#include <hip/hip_runtime.h>

#define N_NODES 100000
#define D 128
#define NTOT (3 * N_NODES)

typedef unsigned short u16;
typedef short s16x8 __attribute__((ext_vector_type(8)));
typedef float f32x4 __attribute__((ext_vector_type(4)));

// ---------------- ws layout ----------------
// ints:   deg @0 (300000) | offs @300000 (300001) | cursor @600001 (300000)
//         csr @900001 (900000) | bsums @1800001 (512) | boffs @1800513 (512)
// bf16:   xb  @byte 7204112 (12.8M u16 = 25.6MB)
//         A1T (+16384) A2T (+32768) A3T (+49152) CwT (+16384)
// total ~33.1 MB of d_ws

__device__ __forceinline__ u16 f2b(float f) {
    union { float f; unsigned u; } v; v.f = f;
    unsigned r = (v.u + 0x7FFFu + ((v.u >> 16) & 1u)) >> 16;
    return (u16)r;
}

// ---------------- converts ----------------

__global__ __launch_bounds__(256) void convert_x(const float* __restrict__ x,
                                                 u16* __restrict__ xb, int n8) {
    int i = blockIdx.x * 256 + threadIdx.x;
    if (i >= n8) return;
    const float4* xp = (const float4*)x;
    float4 a = xp[i * 2], b = xp[i * 2 + 1];
    int4 o;
    o.x = (int)f2b(a.x) | ((int)f2b(a.y) << 16);
    o.y = (int)f2b(a.z) | ((int)f2b(a.w) << 16);
    o.z = (int)f2b(b.x) | ((int)f2b(b.y) << 16);
    o.w = (int)f2b(b.z) | ((int)f2b(b.w) << 16);
    ((int4*)xb)[i] = o;
}

// A is K x 128 row-major; AT is 128 x K row-major (AT[n][k] = A[k][n])
__global__ __launch_bounds__(256) void convert_AT(const float* __restrict__ A,
                                                  u16* __restrict__ AT, int K, int total) {
    int idx = blockIdx.x * 256 + threadIdx.x;
    if (idx >= total) return;
    int n = idx / K;
    int k = idx - n * K;
    AT[idx] = f2b(A[(long)k * D + n]);
}

// ---------------- degree / CSR build (unchanged from R2, verified) ----------------

__global__ __launch_bounds__(256) void zero_deg(int* deg, int n) {
    int i = blockIdx.x * 256 + threadIdx.x;
    if (i < n) deg[i] = 0;
}

__global__ __launch_bounds__(256) void deg_count(const int* __restrict__ ei, int n_edges,
                                                 int shape, int* __restrict__ deg) {
    int e = blockIdx.x * 256 + threadIdx.x;
    if (e < n_edges) {
        int dest = ei[(long)n_edges * shape + (long)e * shape];
        atomicAdd(&deg[dest], 1);
    }
}

__global__ __launch_bounds__(256) void scan_reduce(const int* __restrict__ deg,
                                                   int* __restrict__ bsums, int n) {
    __shared__ int s[256];
    int t = threadIdx.x;
    int base = blockIdx.x * 1024 + t * 4;
    int loc = 0;
#pragma unroll
    for (int r = 0; r < 4; r++) {
        int idx = base + r;
        if (idx < n) loc += deg[idx];
    }
    s[t] = loc;
    for (int off = 128; off > 0; off >>= 1) {
        __syncthreads();
        if (t < off) s[t] += s[t + off];
    }
    if (t == 0) bsums[blockIdx.x] = s[0];
}

__global__ __launch_bounds__(512) void scan_tops(const int* __restrict__ bsums,
                                                 int* __restrict__ boffs,
                                                 int* __restrict__ offs, int nb, int n) {
    __shared__ int s[512];
    int t = threadIdx.x;
    int v = (t < nb) ? bsums[t] : 0;
    s[t] = v;
    for (int off = 1; off < 512; off <<= 1) {
        __syncthreads();
        int x = (t >= off) ? s[t - off] : 0;
        __syncthreads();
        s[t] += x;
    }
    if (t < nb) boffs[t] = s[t] - v;
    if (t == nb - 1) offs[n] = s[t];
}

__global__ __launch_bounds__(256) void scan_final(const int* __restrict__ deg,
                                                  const int* __restrict__ boffs,
                                                  int* __restrict__ offs,
                                                  int* __restrict__ cursor, int n) {
    __shared__ int s[256];
    int t = threadIdx.x;
    int base = blockIdx.x * 1024 + t * 4;
    int v[4], p[4];
#pragma unroll
    for (int r = 0; r < 4; r++) {
        int idx = base + r;
        v[r] = (idx < n) ? deg[idx] : 0;
    }
    p[0] = 0; p[1] = v[0]; p[2] = v[0] + v[1]; p[3] = v[0] + v[1] + v[2];
    int tsum = p[3] + v[3];
    s[t] = tsum;
    for (int off = 1; off < 256; off <<= 1) {
        __syncthreads();
        int x = (t >= off) ? s[t - off] : 0;
        __syncthreads();
        s[t] += x;
    }
    int texcl = s[t] - tsum + boffs[blockIdx.x];
#pragma unroll
    for (int r = 0; r < 4; r++) {
        int idx = base + r;
        if (idx < n) {
            int val = texcl + p[r];
            offs[idx] = val;
            cursor[idx] = val;
        }
    }
}

__global__ __launch_bounds__(256) void scatter_edges(const int* __restrict__ ei, int n_edges,
                                                     int shape, int* __restrict__ cursor,
                                                     int* __restrict__ csr) {
    int e = blockIdx.x * 256 + threadIdx.x;
    if (e < n_edges) {
        int dest = ei[(long)n_edges * shape + (long)e * shape];
        int pos = atomicAdd(&cursor[dest], 1);
        csr[pos] = e;
    }
}

// ---------------- fused MFMA kernel ----------------
// Block owns 64 dest nodes. Tile = 64 edges x 128 cols, mfma_f32_16x16x32_bf16.
// A-frag (edges): LDS Gt[64][40] (pad 8 -> 2-way max bank aliasing, free).
//   layout: A[m=lane&15][k=quad*8+j]  (guide §3, m89-verified)
// B-frag (weights): direct global loads from L2-resident AT[n][K], pipelined 1 k-step ahead.
//   layout: B[k=quad*8+j][n=lane&15]
// C layout: col=lane&15, row=quad*4+reg (m89/m91-verified).
// Epilogue: scale by 1/deg, LDS atomicAdd into accs[64][132] fp32, single coalesced write.

template <int SHAPE, bool DENSE>
__device__ __forceinline__ void process_type(
    const u16* __restrict__ xb, const u16* __restrict__ ATb,
    const int* __restrict__ ei, const int* __restrict__ deg_t,
    const int* __restrict__ offs, const int* __restrict__ csr,
    int n_edges, int tbase, int d0, int dend, int t,
    float (&accs)[64][132], u16 (&Gt)[64][40],
    int (&ssrc)[64][3], float (&sinv)[64], int (&sdl)[64]) {

    constexpr int K = SHAPE * D;
    int start, end;
    if (DENSE) { start = 0; end = dend - d0; }
    else { start = offs[tbase + d0]; end = offs[tbase + dend]; }

    const int lane = t & 63;
    const int wv = t >> 6;
    const int nbase = wv * 32;
    const int quad = lane >> 4;
    const int lrow = lane & 15;

    for (int tile = start; tile < end; tile += 64) {
        __syncthreads();  // prior readers of Gt/meta done
        if (t < 64) {
            int dl = 0;
            float inv = 0.0f;
            if (DENSE) {
                bool valid = (t < end);
                ssrc[t][0] = valid ? (d0 + t) : 0;
                dl = t;
                inv = valid ? 1.0f : 0.0f;
            } else {
                int p = tile + t;
                if (p < end) {
                    int e = csr[p];
                    int dest = ei[(long)n_edges * SHAPE + (long)e * SHAPE];
                    dl = dest - d0;
                    inv = 1.0f / (float)deg_t[dest];
#pragma unroll
                    for (int s = 0; s < SHAPE; s++) ssrc[t][s] = ei[(long)e * SHAPE + s];
                } else {
#pragma unroll
                    for (int s = 0; s < SHAPE; s++) ssrc[t][s] = 0;
                }
            }
            sdl[t] = dl;
            sinv[t] = inv;
        }
        __syncthreads();

        f32x4 accf[4][2];
#pragma unroll
        for (int mi = 0; mi < 4; mi++)
#pragma unroll
            for (int ni = 0; ni < 2; ni++) accf[mi][ni] = (f32x4)(0.0f);

        // prefetch B-frags for k0 = 0 (L2-hot weights)
        s16x8 bcur[2];
#pragma unroll
        for (int ni = 0; ni < 2; ni++) {
            int n = nbase + ni * 16 + lrow;
            bcur[ni] = *(const s16x8*)(ATb + (long)n * K + quad * 8);
        }

#pragma unroll
        for (int k0 = 0; k0 < K; k0 += 32) {
            if (k0) __syncthreads();
            // stage gathered edge tile: 64 rows x 32 k (bf16), 16B per thread
            {
                int el = t >> 2;
                int koff = (t & 3) * 8;
                int slot = k0 >> 7;
                int src = ssrc[el][slot];
                const u16* gp = xb + (long)src * D + (k0 & 127) + koff;
                *(s16x8*)&Gt[el][koff] = *(const s16x8*)gp;
            }
            __syncthreads();

            // pipeline next k-step's B-frags
            s16x8 bnxt[2] = {bcur[0], bcur[1]};
            if (k0 + 32 < K) {
#pragma unroll
                for (int ni = 0; ni < 2; ni++) {
                    int n = nbase + ni * 16 + lrow;
                    bnxt[ni] = *(const s16x8*)(ATb + (long)n * K + (k0 + 32) + quad * 8);
                }
            }

#pragma unroll
            for (int mi = 0; mi < 4; mi++) {
                s16x8 a = *(const s16x8*)&Gt[mi * 16 + lrow][quad * 8];
#pragma unroll
                for (int ni = 0; ni < 2; ni++) {
                    accf[mi][ni] = __builtin_amdgcn_mfma_f32_16x16x32_bf16(
                        a, bcur[ni], accf[mi][ni], 0, 0, 0);
                }
            }
            bcur[0] = bnxt[0];
            bcur[1] = bnxt[1];
        }

        // epilogue: scaled LDS-atomic accumulate (skip invalid rows: sv==0)
#pragma unroll
        for (int mi = 0; mi < 4; mi++) {
#pragma unroll
            for (int reg = 0; reg < 4; reg++) {
                int row = mi * 16 + quad * 4 + reg;
                float sv = sinv[row];
                if (sv != 0.0f) {
                    int dl = sdl[row];
#pragma unroll
                    for (int ni = 0; ni < 2; ni++) {
                        atomicAdd(&accs[dl][nbase + ni * 16 + lrow], accf[mi][ni][reg] * sv);
                    }
                }
            }
        }
    }
}

__global__ __launch_bounds__(256, 4) void fused_kernel(
    const u16* __restrict__ xb, const u16* __restrict__ A1T,
    const u16* __restrict__ A2T, const u16* __restrict__ A3T,
    const u16* __restrict__ CwT, const float* __restrict__ Cb,
    const int* __restrict__ e1, const int* __restrict__ e2, const int* __restrict__ e3,
    const int* __restrict__ deg, const int* __restrict__ offs, const int* __restrict__ csr,
    float* __restrict__ out, int ne1, int ne2, int ne3) {
    __shared__ float accs[64][132];  // 33792 B (pad 4 -> atomic bank spread)
    __shared__ u16 Gt[64][40];       // 5120 B
    __shared__ int ssrc[64][3];
    __shared__ float sinv[64];
    __shared__ int sdl[64];

    const int t = threadIdx.x;
    const int d0 = blockIdx.x * 64;
    const int dend = min(d0 + 64, N_NODES);

    // init accumulator with bias
#pragma unroll
    for (int r = 0; r < 32; r++) {
        int idx = r * 256 + t;
        accs[idx >> 7][idx & 127] = Cb[idx & 127];
    }

    process_type<1, true >(xb, CwT, nullptr, nullptr, nullptr, nullptr, 0, 0,
                           d0, dend, t, accs, Gt, ssrc, sinv, sdl);
    process_type<1, false>(xb, A1T, e1, deg,               offs, csr, ne1, 0,
                           d0, dend, t, accs, Gt, ssrc, sinv, sdl);
    process_type<2, false>(xb, A2T, e2, deg + N_NODES,     offs, csr, ne2, N_NODES,
                           d0, dend, t, accs, Gt, ssrc, sinv, sdl);
    process_type<3, false>(xb, A3T, e3, deg + 2 * N_NODES, offs, csr, ne3, 2 * N_NODES,
                           d0, dend, t, accs, Gt, ssrc, sinv, sdl);

    __syncthreads();
#pragma unroll
    for (int rep = 0; rep < 8; rep++) {
        int f = rep * 256 + t;
        int row = f >> 5;
        int col = (f & 31) * 4;
        if (d0 + row < N_NODES)
            *(float4*)&out[(long)(d0 + row) * D + col] = *(float4*)&accs[row][col];
    }
}

// ---------------- launcher ----------------

extern "C" void kernel_launch(void* const* d_in, const int* in_sizes, int n_in,
                              void* d_out, int out_size, void* d_ws, size_t ws_size,
                              hipStream_t stream) {
    const float* x  = (const float*)d_in[0];
    const float* A1 = (const float*)d_in[1];
    const float* A2 = (const float*)d_in[2];
    const float* A3 = (const float*)d_in[3];
    const float* Cw = (const float*)d_in[4];
    const float* Cb = (const float*)d_in[5];
    const int* e1 = (const int*)d_in[6];
    const int* e2 = (const int*)d_in[7];
    const int* e3 = (const int*)d_in[8];
    float* out = (float*)d_out;

    int* ws = (int*)d_ws;
    int* deg    = ws;
    int* offs   = ws + 300000;
    int* cursor = ws + 600001;
    int* csr    = ws + 900001;
    int* bsums  = ws + 1800001;
    int* boffs  = ws + 1800513;

    u16* xb  = (u16*)((char*)d_ws + 7204112);  // 16B-aligned, after int region
    u16* A1T = xb + (long)N_NODES * D;         // 12.8M u16
    u16* A2T = A1T + 128 * 128;
    u16* A3T = A2T + 128 * 256;
    u16* CwT = A3T + 128 * 384;

    const int NE1 = in_sizes[6] / 2;
    const int NE2 = in_sizes[7] / (2 * 2);
    const int NE3 = in_sizes[8] / (2 * 3);
    const int n = NTOT;
    const int NB = (n + 1023) / 1024;

    // converts (bf16 staging)
    convert_x<<<(N_NODES * D / 8 + 255) / 256, 256, 0, stream>>>(x, xb, N_NODES * D / 8);
    convert_AT<<<(128 * 128 + 255) / 256, 256, 0, stream>>>(A1, A1T, 128, 128 * 128);
    convert_AT<<<(128 * 256 + 255) / 256, 256, 0, stream>>>(A2, A2T, 256, 128 * 256);
    convert_AT<<<(128 * 384 + 255) / 256, 256, 0, stream>>>(A3, A3T, 384, 128 * 384);
    convert_AT<<<(128 * 128 + 255) / 256, 256, 0, stream>>>(Cw, CwT, 128, 128 * 128);

    // degrees
    zero_deg<<<(n + 255) / 256, 256, 0, stream>>>(deg, n);
    deg_count<<<(NE1 + 255) / 256, 256, 0, stream>>>(e1, NE1, 1, deg);
    deg_count<<<(NE2 + 255) / 256, 256, 0, stream>>>(e2, NE2, 2, deg + N_NODES);
    deg_count<<<(NE3 + 255) / 256, 256, 0, stream>>>(e3, NE3, 3, deg + 2 * N_NODES);

    // exclusive scan -> offs, cursor
    scan_reduce<<<NB, 256, 0, stream>>>(deg, bsums, n);
    scan_tops<<<1, 512, 0, stream>>>(bsums, boffs, offs, NB, n);
    scan_final<<<NB, 256, 0, stream>>>(deg, boffs, offs, cursor, n);

    // bucket edges by (type, dest)
    scatter_edges<<<(NE1 + 255) / 256, 256, 0, stream>>>(e1, NE1, 1, cursor, csr);
    scatter_edges<<<(NE2 + 255) / 256, 256, 0, stream>>>(e2, NE2, 2, cursor + N_NODES, csr);
    scatter_edges<<<(NE3 + 255) / 256, 256, 0, stream>>>(e3, NE3, 3, cursor + 2 * N_NODES, csr);

    // fused MFMA compute
    fused_kernel<<<(N_NODES + 63) / 64, 256, 0, stream>>>(
        xb, A1T, A2T, A3T, CwT, Cb, e1, e2, e3, deg, offs, csr, out, NE1, NE2, NE3);
}

// Round 4
// 437.962 us; speedup vs baseline: 4.8799x; 2.4825x over previous
//
#include <hip/hip_runtime.h>

#define N_NODES 100000
#define D 128
#define NND 12800000  // N_NODES * D
#define NTOT (3 * N_NODES)

typedef unsigned short u16;
typedef short s16x8 __attribute__((ext_vector_type(8)));
typedef float f32x4 __attribute__((ext_vector_type(4)));

// ---------------- ws layout ----------------
// ints:  deg @0 (300000) | offs @300000 (300001) | cursor @600001 (300000)
//        csr1 @900001 (400000) | csr2 @1300001 (600000) | csr3 @1900001 (600000)
//        bsums @2500001 (512) | boffs @2500513 (512)       -> 10.0 MB
// u16:   AT @byte 10004224: 7 mats x 16384 (Cw, A1s0, A2s0, A2s1, A3s0..2) -> 229 KB
//        Y  @byte 10233600: 3 x NND u16 (slot-major)                        -> 76.8 MB
// total ~87 MB

__device__ __forceinline__ u16 f2b(float f) {
    union { float f; unsigned u; } v; v.f = f;
    unsigned r = (v.u + 0x7FFFu + ((v.u >> 16) & 1u)) >> 16;
    return (u16)r;
}

// ---------------- weight transpose+convert (7 slot mats of 128x128) ----------------
// m: 0=Cw, 1=A1s0, 2..3=A2 slots, 4..6=A3 slots. AT[m][n][k] = A[slot*128+k][n]

__global__ __launch_bounds__(256) void convert_all(
    const float* __restrict__ A1, const float* __restrict__ A2,
    const float* __restrict__ A3, const float* __restrict__ Cw,
    u16* __restrict__ ATb) {
    int m = blockIdx.x >> 6;
    int idx = (blockIdx.x & 63) * 256 + threadIdx.x;  // 0..16383
    int n = idx >> 7, kk = idx & 127;
    const float* src; int srow;
    if (m == 0)      { src = Cw; srow = kk; }
    else if (m == 1) { src = A1; srow = kk; }
    else if (m < 4)  { src = A2; srow = (m - 2) * 128 + kk; }
    else             { src = A3; srow = (m - 4) * 128 + kk; }
    ATb[m * 16384 + n * 128 + kk] = f2b(src[(long)srow * 128 + n]);
}

// ---------------- degree / CSR build ----------------

__global__ __launch_bounds__(256) void zero_deg(int* deg, int n) {
    int i = blockIdx.x * 256 + threadIdx.x;
    if (i < n) deg[i] = 0;
}

__global__ __launch_bounds__(256) void deg_count(const int* __restrict__ ei, int n_edges,
                                                 int shape, int* __restrict__ deg) {
    int e = blockIdx.x * 256 + threadIdx.x;
    if (e < n_edges) {
        int dest = ei[(long)n_edges * shape + (long)e * shape];
        atomicAdd(&deg[dest], 1);
    }
}

__global__ __launch_bounds__(256) void scan_reduce(const int* __restrict__ deg,
                                                   int* __restrict__ bsums, int n) {
    __shared__ int s[256];
    int t = threadIdx.x;
    int base = blockIdx.x * 1024 + t * 4;
    int loc = 0;
#pragma unroll
    for (int r = 0; r < 4; r++) {
        int idx = base + r;
        if (idx < n) loc += deg[idx];
    }
    s[t] = loc;
    for (int off = 128; off > 0; off >>= 1) {
        __syncthreads();
        if (t < off) s[t] += s[t + off];
    }
    if (t == 0) bsums[blockIdx.x] = s[0];
}

__global__ __launch_bounds__(512) void scan_tops(const int* __restrict__ bsums,
                                                 int* __restrict__ boffs,
                                                 int* __restrict__ offs, int nb, int n) {
    __shared__ int s[512];
    int t = threadIdx.x;
    int v = (t < nb) ? bsums[t] : 0;
    s[t] = v;
    for (int off = 1; off < 512; off <<= 1) {
        __syncthreads();
        int x = (t >= off) ? s[t - off] : 0;
        __syncthreads();
        s[t] += x;
    }
    if (t < nb) boffs[t] = s[t] - v;
    if (t == nb - 1) offs[n] = s[t];
}

__global__ __launch_bounds__(256) void scan_final(const int* __restrict__ deg,
                                                  const int* __restrict__ boffs,
                                                  int* __restrict__ offs,
                                                  int* __restrict__ cursor, int n) {
    __shared__ int s[256];
    int t = threadIdx.x;
    int base = blockIdx.x * 1024 + t * 4;
    int v[4], p[4];
#pragma unroll
    for (int r = 0; r < 4; r++) {
        int idx = base + r;
        v[r] = (idx < n) ? deg[idx] : 0;
    }
    p[0] = 0; p[1] = v[0]; p[2] = v[0] + v[1]; p[3] = v[0] + v[1] + v[2];
    int tsum = p[3] + v[3];
    s[t] = tsum;
    for (int off = 1; off < 256; off <<= 1) {
        __syncthreads();
        int x = (t >= off) ? s[t - off] : 0;
        __syncthreads();
        s[t] += x;
    }
    int texcl = s[t] - tsum + boffs[blockIdx.x];
#pragma unroll
    for (int r = 0; r < 4; r++) {
        int idx = base + r;
        if (idx < n) {
            int val = texcl + p[r];
            offs[idx] = val;
            cursor[idx] = val;
        }
    }
}

// scatter SOURCE tuples grouped by (type,dest); csr_t index is type-local (minus base)
template <int SHAPE>
__global__ __launch_bounds__(256) void scatter_src(const int* __restrict__ ei, int n_edges,
                                                   int* __restrict__ cursor, int base,
                                                   int* __restrict__ csr) {
    int e = blockIdx.x * 256 + threadIdx.x;
    if (e < n_edges) {
        int dest = ei[(long)n_edges * SHAPE + (long)e * SHAPE];
        int pos = atomicAdd(&cursor[dest], 1) - base;
#pragma unroll
        for (int s = 0; s < SHAPE; s++) csr[pos * SHAPE + s] = ei[(long)e * SHAPE + s];
    }
}

// ---------------- phase 1: dense GEMMs  Y_w = x @ A_w  (bf16 MFMA) ----------------
// Block: 64 rows of x staged once (fp32->bf16 in LDS), A-frags hoisted to regs,
// NW weight mats multiplied back-to-back (B-frags from L2-hot AT).
// C layout: col=lane&15, row=quad*4+reg (m89/m91-verified; numerically validated R3).

template <int NW, bool DENSE>
__global__ __launch_bounds__(256) void gemm_y(
    const float* __restrict__ x, const u16* __restrict__ AT,
    const float* __restrict__ Cb, u16* __restrict__ Yout, float* __restrict__ outf) {
    __shared__ u16 Xs[4][64][40];  // 4 k-chunks of 32, pad 8 (R3-proven pattern)
    const int t = threadIdx.x;
    const int d0 = blockIdx.x * 64;

    // stage + convert x tile
#pragma unroll
    for (int i = 0; i < 8; i++) {
        int f = i * 256 + t;       // float4 index within 64x128 tile
        int row = f >> 5;
        int k4 = f & 31;
        int rs = d0 + row < N_NODES ? d0 + row : N_NODES - 1;
        float4 v = *(const float4*)&x[(long)rs * D + k4 * 4];
        int chunk = k4 >> 3, kk = (k4 & 7) * 4;
        u16* p = &Xs[chunk][row][kk];
        p[0] = f2b(v.x); p[1] = f2b(v.y); p[2] = f2b(v.z); p[3] = f2b(v.w);
    }
    __syncthreads();

    const int lane = t & 63, wv = t >> 6;
    const int nbase = wv * 32, quad = lane >> 4, lrow = lane & 15;

    s16x8 afrag[4][4];
#pragma unroll
    for (int mi = 0; mi < 4; mi++)
#pragma unroll
        for (int c = 0; c < 4; c++)
            afrag[mi][c] = *(const s16x8*)&Xs[c][mi * 16 + lrow][quad * 8];

#pragma unroll
    for (int w = 0; w < NW; w++) {
        const u16* B = AT + w * 16384;
        s16x8 bfrag[2][4];
#pragma unroll
        for (int ni = 0; ni < 2; ni++)
#pragma unroll
            for (int c = 0; c < 4; c++)
                bfrag[ni][c] = *(const s16x8*)(B + (long)(nbase + ni * 16 + lrow) * 128 +
                                               c * 32 + quad * 8);
        f32x4 acc[4][2];
#pragma unroll
        for (int mi = 0; mi < 4; mi++)
#pragma unroll
            for (int ni = 0; ni < 2; ni++) acc[mi][ni] = (f32x4)(0.0f);
#pragma unroll
        for (int c = 0; c < 4; c++)
#pragma unroll
            for (int mi = 0; mi < 4; mi++)
#pragma unroll
                for (int ni = 0; ni < 2; ni++)
                    acc[mi][ni] = __builtin_amdgcn_mfma_f32_16x16x32_bf16(
                        afrag[mi][c], bfrag[ni][c], acc[mi][ni], 0, 0, 0);
        // epilogue
#pragma unroll
        for (int mi = 0; mi < 4; mi++)
#pragma unroll
            for (int ni = 0; ni < 2; ni++)
#pragma unroll
                for (int reg = 0; reg < 4; reg++) {
                    int row = mi * 16 + quad * 4 + reg;
                    int col = nbase + ni * 16 + lrow;
                    if (d0 + row < N_NODES) {
                        long idx = (long)(d0 + row) * D + col;
                        if (DENSE) outf[idx] = acc[mi][ni][reg] + Cb[col];
                        else Yout[(long)w * NND + idx] = f2b(acc[mi][ni][reg]);
                    }
                }
    }
}

// ---------------- phase 2: gather-sum per dest, RMW out ----------------
// One wave per dest (grid-stride). Batch 4 edges -> up to 4*SHAPE row loads in flight.
// Lane owns cols [2*lane, 2*lane+1] (one bf16x2 word per row).

template <int SHAPE>
__global__ __launch_bounds__(256) void gather_acc(
    const u16* __restrict__ Y, const int* __restrict__ csr,
    const int* __restrict__ offs_t, int base, float* __restrict__ out) {
    const int lane = threadIdx.x & 63;
    int wid = blockIdx.x * 4 + (threadIdx.x >> 6);
    const int nw = gridDim.x * 4;
    for (int d = wid; d < N_NODES; d += nw) {
        int lo = offs_t[d] - base;
        int hi = offs_t[d + 1] - base;
        int cnt = hi - lo;
        if (cnt <= 0) continue;
        float a0 = 0.0f, a1 = 0.0f;
        int p = lo;
        for (; p + 4 <= hi; p += 4) {
            int sv[4][SHAPE];
#pragma unroll
            for (int i = 0; i < 4; i++)
#pragma unroll
                for (int s = 0; s < SHAPE; s++) sv[i][s] = csr[(p + i) * SHAPE + s];
            unsigned rw[4][SHAPE];
#pragma unroll
            for (int i = 0; i < 4; i++)
#pragma unroll
                for (int s = 0; s < SHAPE; s++)
                    rw[i][s] = *(const unsigned*)(Y + (long)s * NND +
                                                  (long)sv[i][s] * D + lane * 2);
#pragma unroll
            for (int i = 0; i < 4; i++)
#pragma unroll
                for (int s = 0; s < SHAPE; s++) {
                    a0 += __uint_as_float(rw[i][s] << 16);
                    a1 += __uint_as_float(rw[i][s] & 0xFFFF0000u);
                }
        }
        for (; p < hi; p++) {
            int sv[SHAPE];
#pragma unroll
            for (int s = 0; s < SHAPE; s++) sv[s] = csr[p * SHAPE + s];
#pragma unroll
            for (int s = 0; s < SHAPE; s++) {
                unsigned w = *(const unsigned*)(Y + (long)s * NND + (long)sv[s] * D + lane * 2);
                a0 += __uint_as_float(w << 16);
                a1 += __uint_as_float(w & 0xFFFF0000u);
            }
        }
        float inv = 1.0f / (float)cnt;
        float2* op = (float2*)&out[(long)d * D + lane * 2];
        float2 o = *op;
        o.x += a0 * inv;
        o.y += a1 * inv;
        *op = o;
    }
}

// ---------------- launcher ----------------

extern "C" void kernel_launch(void* const* d_in, const int* in_sizes, int n_in,
                              void* d_out, int out_size, void* d_ws, size_t ws_size,
                              hipStream_t stream) {
    const float* x  = (const float*)d_in[0];
    const float* A1 = (const float*)d_in[1];
    const float* A2 = (const float*)d_in[2];
    const float* A3 = (const float*)d_in[3];
    const float* Cw = (const float*)d_in[4];
    const float* Cb = (const float*)d_in[5];
    const int* e1 = (const int*)d_in[6];
    const int* e2 = (const int*)d_in[7];
    const int* e3 = (const int*)d_in[8];
    float* out = (float*)d_out;

    int* ws = (int*)d_ws;
    int* deg    = ws;
    int* offs   = ws + 300000;
    int* cursor = ws + 600001;
    int* csr1   = ws + 900001;
    int* csr2   = ws + 1300001;
    int* csr3   = ws + 1900001;
    int* bsums  = ws + 2500001;
    int* boffs  = ws + 2500513;

    u16* ATb = (u16*)((char*)d_ws + 10004224);
    u16* ATCw = ATb;
    u16* AT1  = ATb + 16384;
    u16* AT2  = ATb + 32768;
    u16* AT3  = ATb + 65536;
    u16* Y    = (u16*)((char*)d_ws + 10233600);  // 3 x NND u16

    const int NE1 = in_sizes[6] / 2;
    const int NE2 = in_sizes[7] / (2 * 2);
    const int NE3 = in_sizes[8] / (2 * 3);
    const int n = NTOT;
    const int NB = (n + 1023) / 1024;
    const int GB = (N_NODES + 63) / 64;  // 1563

    // weight transpose+convert (7 slot mats)
    convert_all<<<448, 256, 0, stream>>>(A1, A2, A3, Cw, ATb);

    // degrees
    zero_deg<<<(n + 255) / 256, 256, 0, stream>>>(deg, n);
    deg_count<<<(NE1 + 255) / 256, 256, 0, stream>>>(e1, NE1, 1, deg);
    deg_count<<<(NE2 + 255) / 256, 256, 0, stream>>>(e2, NE2, 2, deg + N_NODES);
    deg_count<<<(NE3 + 255) / 256, 256, 0, stream>>>(e3, NE3, 3, deg + 2 * N_NODES);

    // exclusive scan -> offs, cursor
    scan_reduce<<<NB, 256, 0, stream>>>(deg, bsums, n);
    scan_tops<<<1, 512, 0, stream>>>(bsums, boffs, offs, NB, n);
    scan_final<<<NB, 256, 0, stream>>>(deg, boffs, offs, cursor, n);

    // bucket source-tuples by (type,dest)
    scatter_src<1><<<(NE1 + 255) / 256, 256, 0, stream>>>(e1, NE1, cursor, 0, csr1);
    scatter_src<2><<<(NE2 + 255) / 256, 256, 0, stream>>>(e2, NE2, cursor + N_NODES, NE1, csr2);
    scatter_src<3><<<(NE3 + 255) / 256, 256, 0, stream>>>(e3, NE3, cursor + 2 * N_NODES,
                                                          NE1 + NE2, csr3);

    // dense term: out = x @ Cw + Cb
    gemm_y<1, true><<<GB, 256, 0, stream>>>(x, ATCw, Cb, nullptr, out);

    // r1: Y0 = x @ A1 ; gather
    gemm_y<1, false><<<GB, 256, 0, stream>>>(x, AT1, nullptr, Y, nullptr);
    gather_acc<1><<<2048, 256, 0, stream>>>(Y, csr1, offs, 0, out);

    // r2: Y0,Y1 = x @ A2 slots ; gather
    gemm_y<2, false><<<GB, 256, 0, stream>>>(x, AT2, nullptr, Y, nullptr);
    gather_acc<2><<<2048, 256, 0, stream>>>(Y, csr2, offs + N_NODES, NE1, out);

    // r3: Y0..Y2 = x @ A3 slots ; gather
    gemm_y<3, false><<<GB, 256, 0, stream>>>(x, AT3, nullptr, Y, nullptr);
    gather_acc<3><<<2048, 256, 0, stream>>>(Y, csr3, offs + 2 * N_NODES, NE1 + NE2, out);
}

// Round 5
// 356.574 us; speedup vs baseline: 5.9937x; 1.2282x over previous
//
#include <hip/hip_runtime.h>

#define N_NODES 100000
#define D 128
#define NND 12800000L  // N_NODES * D

typedef unsigned short u16;
typedef short s16x8 __attribute__((ext_vector_type(8)));
typedef float f32x4 __attribute__((ext_vector_type(4)));

// ---------------- ws layout ----------------
// ints (4B):
//   deg    @ 0        (300000)   per-type in-degree [type*100000 + d]
//   offs   @ 300000   (100001)   unified entry-list exclusive scan (+sentinel)
//   cursor @ 400001   (100000)
//   bsums  @ 500001   (512)
//   boffs  @ 500513   (512)
// int2 ents @ byte 2004160  (1,700,000 x 8B = 13.6 MB)  {rowidx, scale}
// u16  AT   @ byte 15604224 (7 x 16384 = 229 KB)  transposed bf16 weights
// u16  Y    @ byte 15833600 (7 x NND = 179.2 MB)  slots: A1s0,A2s0,A2s1,A3s0..2,Cw
// total ~195.1 MB

#define ENTS_OFF 2004160L
#define AT_OFF   15604224L
#define Y_OFF    15833600L

__device__ __forceinline__ u16 f2b(float f) {
    union { float f; unsigned u; } v; v.f = f;
    unsigned r = (v.u + 0x7FFFu + ((v.u >> 16) & 1u)) >> 16;
    return (u16)r;
}
__device__ __forceinline__ float blo(unsigned w) { return __uint_as_float(w << 16); }
__device__ __forceinline__ float bhi(unsigned w) { return __uint_as_float(w & 0xFFFF0000u); }

// ---------------- K1: zero degrees + transpose/convert 7 weight mats ----------------
// blocks [0,293): zero deg. blocks [293, 293+448): convert (7 mats x 64 blocks).
// slot m: 0=A1s0, 1..2=A2, 3..5=A3, 6=Cw.  AT[m][n][k] = A[slot_k][n] (bf16)

__global__ __launch_bounds__(256) void init_kernel(
    const float* __restrict__ A1, const float* __restrict__ A2,
    const float* __restrict__ A3, const float* __restrict__ Cw,
    u16* __restrict__ ATb, int* __restrict__ deg) {
    int b = blockIdx.x, t = threadIdx.x;
    if (b < 293) {
        int i0 = (b * 256 + t) * 4;
#pragma unroll
        for (int r = 0; r < 4; r++)
            if (i0 + r < 300000) deg[i0 + r] = 0;
        return;
    }
    int mb = b - 293;
    int m = mb >> 6;
    int idx = (mb & 63) * 256 + t;  // 0..16383
    int n = idx >> 7, kk = idx & 127;
    const float* src; int srow;
    if (m == 0)      { src = A1; srow = kk; }
    else if (m < 3)  { src = A2; srow = (m - 1) * 128 + kk; }
    else if (m < 6)  { src = A3; srow = (m - 3) * 128 + kk; }
    else             { src = Cw; srow = kk; }
    ATb[m * 16384 + n * 128 + kk] = f2b(src[(long)srow * 128 + n]);
}

// ---------------- K2: per-type in-degree (one pass over all edges) ----------------

__global__ __launch_bounds__(256) void deg_all(
    const int* __restrict__ e1, const int* __restrict__ e2, const int* __restrict__ e3,
    int ne1, int ne2, int ne3, int* __restrict__ deg) {
    int g = blockIdx.x * 256 + threadIdx.x;
    if (g < ne1) {
        atomicAdd(&deg[e1[ne1 + g]], 1);
    } else if (g < ne1 + ne2) {
        int e = g - ne1;
        atomicAdd(&deg[N_NODES + e2[ne2 * 2 + e * 2]], 1);
    } else if (g < ne1 + ne2 + ne3) {
        int e = g - ne1 - ne2;
        atomicAdd(&deg[2 * N_NODES + e3[ne3 * 3 + e * 3]], 1);
    }
}

// unified per-dest entry count: u[d] = 1(self) + c1 + 2*c2 + 3*c3
__device__ __forceinline__ int ucnt(const int* deg, int d) {
    return 1 + deg[d] + 2 * deg[N_NODES + d] + 3 * deg[2 * N_NODES + d];
}

// ---------------- K3..K5: exclusive scan of ucnt over 100000 ----------------

__global__ __launch_bounds__(256) void scan_reduce_u(const int* __restrict__ deg,
                                                     int* __restrict__ bsums, int n) {
    __shared__ int s[256];
    int t = threadIdx.x;
    int base = blockIdx.x * 1024 + t * 4;
    int loc = 0;
#pragma unroll
    for (int r = 0; r < 4; r++) {
        int idx = base + r;
        if (idx < n) loc += ucnt(deg, idx);
    }
    s[t] = loc;
    for (int off = 128; off > 0; off >>= 1) {
        __syncthreads();
        if (t < off) s[t] += s[t + off];
    }
    if (t == 0) bsums[blockIdx.x] = s[0];
}

__global__ __launch_bounds__(512) void scan_tops(const int* __restrict__ bsums,
                                                 int* __restrict__ boffs,
                                                 int* __restrict__ offs, int nb, int n) {
    __shared__ int s[512];
    int t = threadIdx.x;
    int v = (t < nb) ? bsums[t] : 0;
    s[t] = v;
    for (int off = 1; off < 512; off <<= 1) {
        __syncthreads();
        int x = (t >= off) ? s[t - off] : 0;
        __syncthreads();
        s[t] += x;
    }
    if (t < nb) boffs[t] = s[t] - v;
    if (t == nb - 1) offs[n] = s[t];
}

// final scan; also seeds the self entry (dense term, slot 6) and cursor = offs+1
__global__ __launch_bounds__(256) void scan_final_u(
    const int* __restrict__ deg, const int* __restrict__ boffs,
    int* __restrict__ offs, int* __restrict__ cursor, int2* __restrict__ ents, int n) {
    __shared__ int s[256];
    int t = threadIdx.x;
    int base = blockIdx.x * 1024 + t * 4;
    int v[4], p[4];
#pragma unroll
    for (int r = 0; r < 4; r++) {
        int idx = base + r;
        v[r] = (idx < n) ? ucnt(deg, idx) : 0;
    }
    p[0] = 0; p[1] = v[0]; p[2] = v[0] + v[1]; p[3] = v[0] + v[1] + v[2];
    int tsum = p[3] + v[3];
    s[t] = tsum;
    for (int off = 1; off < 256; off <<= 1) {
        __syncthreads();
        int x = (t >= off) ? s[t - off] : 0;
        __syncthreads();
        s[t] += x;
    }
    int texcl = s[t] - tsum + boffs[blockIdx.x];
#pragma unroll
    for (int r = 0; r < 4; r++) {
        int idx = base + r;
        if (idx < n) {
            int val = texcl + p[r];
            offs[idx] = val;
            cursor[idx] = val + 1;  // slot for self entry consumed
            ents[val] = make_int2(6 * N_NODES + idx, __float_as_int(1.0f));
        }
    }
}

// ---------------- K6: scatter unified entries {rowidx, 1/deg_t} ----------------

__global__ __launch_bounds__(256) void scatter_all(
    const int* __restrict__ e1, const int* __restrict__ e2, const int* __restrict__ e3,
    int ne1, int ne2, int ne3, const int* __restrict__ deg,
    int* __restrict__ cursor, int2* __restrict__ ents) {
    int g = blockIdx.x * 256 + threadIdx.x;
    if (g < ne1) {
        int dest = e1[ne1 + g];
        float sc = 1.0f / (float)deg[dest];
        int pos = atomicAdd(&cursor[dest], 1);
        ents[pos] = make_int2(e1[g], __float_as_int(sc));  // slot 0
    } else if (g < ne1 + ne2) {
        int e = g - ne1;
        int dest = e2[ne2 * 2 + e * 2];
        float sc = 1.0f / (float)deg[N_NODES + dest];
        int pos = atomicAdd(&cursor[dest], 2);
        ents[pos]     = make_int2(1 * N_NODES + e2[e * 2],     __float_as_int(sc));
        ents[pos + 1] = make_int2(2 * N_NODES + e2[e * 2 + 1], __float_as_int(sc));
    } else if (g < ne1 + ne2 + ne3) {
        int e = g - ne1 - ne2;
        int dest = e3[ne3 * 3 + e * 3];
        float sc = 1.0f / (float)deg[2 * N_NODES + dest];
        int pos = atomicAdd(&cursor[dest], 3);
#pragma unroll
        for (int s = 0; s < 3; s++)
            ents[pos + s] = make_int2((3 + s) * N_NODES + e3[e * 3 + s], __float_as_int(sc));
    }
}

// ---------------- K7: one GEMM pass — Y[w] = x @ A_w for all 7 slots ----------------
// 64-row x tile staged once (fp32->bf16 LDS), afrag in regs, 7 B-mats from L2,
// LDS-bounce epilogue for coalesced bf16 Y stores.
// MFMA C layout: col=lane&15, row=quad*4+reg (R3/R4-validated).

__global__ __launch_bounds__(256) void gemm_all(
    const float* __restrict__ x, const u16* __restrict__ AT, u16* __restrict__ Y) {
    __shared__ float smemf[64 * 132];  // 33792 B; first 20480 B aliased as Xs
    typedef u16 XsT[64][40];
    XsT* Xs = reinterpret_cast<XsT*>(smemf);

    const int t = threadIdx.x;
    const int d0 = blockIdx.x * 64;

    // stage + convert x tile (clamped rows)
#pragma unroll
    for (int i = 0; i < 8; i++) {
        int f = i * 256 + t;
        int row = f >> 5;
        int k4 = f & 31;
        int rs = d0 + row < N_NODES ? d0 + row : N_NODES - 1;
        float4 v = *(const float4*)&x[(long)rs * D + k4 * 4];
        int chunk = k4 >> 3, kk = (k4 & 7) * 4;
        u16* p = &Xs[chunk][row][kk];
        p[0] = f2b(v.x); p[1] = f2b(v.y); p[2] = f2b(v.z); p[3] = f2b(v.w);
    }
    __syncthreads();

    const int lane = t & 63, wv = t >> 6;
    const int nbase = wv * 32, quad = lane >> 4, lrow = lane & 15;

    s16x8 afrag[4][4];
#pragma unroll
    for (int mi = 0; mi < 4; mi++)
#pragma unroll
        for (int c = 0; c < 4; c++)
            afrag[mi][c] = *(const s16x8*)&Xs[c][mi * 16 + lrow][quad * 8];

    for (int w = 0; w < 7; w++) {
        const u16* B = AT + w * 16384;
        s16x8 bfrag[2][4];
#pragma unroll
        for (int ni = 0; ni < 2; ni++)
#pragma unroll
            for (int c = 0; c < 4; c++)
                bfrag[ni][c] = *(const s16x8*)(B + (long)(nbase + ni * 16 + lrow) * 128 +
                                               c * 32 + quad * 8);
        f32x4 acc[4][2];
#pragma unroll
        for (int mi = 0; mi < 4; mi++)
#pragma unroll
            for (int ni = 0; ni < 2; ni++) acc[mi][ni] = (f32x4)(0.0f);
#pragma unroll
        for (int c = 0; c < 4; c++)
#pragma unroll
            for (int mi = 0; mi < 4; mi++)
#pragma unroll
                for (int ni = 0; ni < 2; ni++)
                    acc[mi][ni] = __builtin_amdgcn_mfma_f32_16x16x32_bf16(
                        afrag[mi][c], bfrag[ni][c], acc[mi][ni], 0, 0, 0);

        // bounce through LDS for coalesced bf16 stores
        __syncthreads();  // prior readers (afrag / previous store pass) done
#pragma unroll
        for (int mi = 0; mi < 4; mi++)
#pragma unroll
            for (int ni = 0; ni < 2; ni++)
#pragma unroll
                for (int reg = 0; reg < 4; reg++) {
                    int row = mi * 16 + quad * 4 + reg;
                    int col = nbase + ni * 16 + lrow;
                    smemf[row * 132 + col] = acc[mi][ni][reg];
                }
        __syncthreads();
        u16* Yw = Y + (long)w * NND;
#pragma unroll
        for (int i = 0; i < 8; i++) {
            int f = i * 256 + t;
            int row = f >> 5;
            int col = (f & 31) * 4;
            if (d0 + row < N_NODES) {
                float4 v = *(const float4*)&smemf[row * 132 + col];
                unsigned o0 = (unsigned)f2b(v.x) | ((unsigned)f2b(v.y) << 16);
                unsigned o1 = (unsigned)f2b(v.z) | ((unsigned)f2b(v.w) << 16);
                uint2 o = make_uint2(o0, o1);
                *(uint2*)(Yw + (long)(d0 + row) * D + col) = o;
            }
        }
        __syncthreads();  // stores read smemf; next w overwrites
    }
}

// ---------------- K8: unified gather — out[d] = Cb + sum(scale * Y[rowidx]) ----------------
// One wave per dest (grid-stride). Batched 8-deep clamped load pipeline.
// Lane owns cols [2*lane, 2*lane+1].

__global__ __launch_bounds__(256) void gather_all(
    const u16* __restrict__ Y, const int2* __restrict__ ents,
    const int* __restrict__ offs, const float* __restrict__ Cb,
    float* __restrict__ out) {
    const int lane = threadIdx.x & 63;
    const int wv = __builtin_amdgcn_readfirstlane(threadIdx.x >> 6);
    int wid = blockIdx.x * 4 + wv;
    const int nw = gridDim.x * 4;
    const float cb0 = Cb[lane * 2];
    const float cb1 = Cb[lane * 2 + 1];

    for (int d = wid; d < N_NODES; d += nw) {
        int lo = offs[d];
        int hi = offs[d + 1];
        float a0 = 0.0f, a1 = 0.0f;
        for (int p = lo; p < hi; p += 8) {
            int2 e[8];
#pragma unroll
            for (int i = 0; i < 8; i++) {
                int q = p + i;
                e[i] = ents[q < hi ? q : hi - 1];
            }
            unsigned w[8];
#pragma unroll
            for (int i = 0; i < 8; i++)
                w[i] = *(const unsigned*)(Y + (long)e[i].x * D + lane * 2);
#pragma unroll
            for (int i = 0; i < 8; i++) {
                float s = (p + i < hi) ? __int_as_float(e[i].y) : 0.0f;
                a0 = fmaf(s, blo(w[i]), a0);
                a1 = fmaf(s, bhi(w[i]), a1);
            }
        }
        *(float2*)&out[(long)d * D + lane * 2] = make_float2(a0 + cb0, a1 + cb1);
    }
}

// ---------------- launcher ----------------

extern "C" void kernel_launch(void* const* d_in, const int* in_sizes, int n_in,
                              void* d_out, int out_size, void* d_ws, size_t ws_size,
                              hipStream_t stream) {
    const float* x  = (const float*)d_in[0];
    const float* A1 = (const float*)d_in[1];
    const float* A2 = (const float*)d_in[2];
    const float* A3 = (const float*)d_in[3];
    const float* Cw = (const float*)d_in[4];
    const float* Cb = (const float*)d_in[5];
    const int* e1 = (const int*)d_in[6];
    const int* e2 = (const int*)d_in[7];
    const int* e3 = (const int*)d_in[8];
    float* out = (float*)d_out;

    int* ws = (int*)d_ws;
    int* deg    = ws;
    int* offs   = ws + 300000;
    int* cursor = ws + 400001;
    int* bsums  = ws + 500001;
    int* boffs  = ws + 500513;
    int2* ents  = (int2*)((char*)d_ws + ENTS_OFF);
    u16* ATb    = (u16*)((char*)d_ws + AT_OFF);
    u16* Y      = (u16*)((char*)d_ws + Y_OFF);

    const int NE1 = in_sizes[6] / 2;        // 400000
    const int NE2 = in_sizes[7] / (2 * 2);  // 300000
    const int NE3 = in_sizes[8] / (2 * 3);  // 200000
    const int NET = NE1 + NE2 + NE3;        // 900000
    const int n = N_NODES;
    const int NB = (n + 1023) / 1024;       // 98

    init_kernel<<<293 + 448, 256, 0, stream>>>(A1, A2, A3, Cw, ATb, deg);
    deg_all<<<(NET + 255) / 256, 256, 0, stream>>>(e1, e2, e3, NE1, NE2, NE3, deg);
    scan_reduce_u<<<NB, 256, 0, stream>>>(deg, bsums, n);
    scan_tops<<<1, 512, 0, stream>>>(bsums, boffs, offs, NB, n);
    scan_final_u<<<NB, 256, 0, stream>>>(deg, boffs, offs, cursor, ents, n);
    scatter_all<<<(NET + 255) / 256, 256, 0, stream>>>(e1, e2, e3, NE1, NE2, NE3,
                                                       deg, cursor, ents);
    gemm_all<<<(N_NODES + 63) / 64, 256, 0, stream>>>(x, ATb, Y);
    gather_all<<<2048, 256, 0, stream>>>(Y, ents, offs, Cb, out);
}